// Round 4
// baseline (87.745 us; speedup 1.0000x reference)
//
#include <hip/hip_runtime.h>

#define BSZ 512
#define EPSF 1e-5f
#define KT   32          // k-chunk per block
#define NS   16          // split-k factor (NS*KT = 512)
#define TR   128         // tile rows per block
#define TC   64          // tile cols per block
#define ASTR 132         // As stride (floats): mult of 4 (16B-aligned b128), mod 32 = 4
#define BSTR 68          // Bs stride: mult of 4, mod 32 = 4

// ws layout (floats): [0..2] accS/accC/accV (unused slots kept), [3] counter(int),
// [8 .. 8+3*512) per-anchor partials, [2048 ..) P[NS][512][512]
#define WS_PARTIAL 8
#define WS_P       2048

__device__ __forceinline__ float dist_xform(float v) {
    v = fmaxf(v, 0.0f);
    float z = (v == 0.0f) ? 1.0f : 0.0f;   // zmask per reference
    v = sqrtf(v + z * EPSF) + EPSF;
    return v * (1.0f - z);
}

// ---- Kernel 1: partial squared distances. 128x64 tile, 8x4 micro, split-k. ----
// P[s][i][j] = sum_{k in chunk s} (E[i,k]-E[j,k])^2
__global__ __launch_bounds__(256) void dsq_kernel(const float* __restrict__ E,
                                                  float* __restrict__ ws) {
    // zero the reduction cells for kernel 2 (exactly one thread; no one else
    // touches these in this kernel; kernel-boundary flush makes it visible)
    if (blockIdx.x == 0 && blockIdx.y == 0 && blockIdx.z == 0 && threadIdx.x == 0) {
        ((int*)ws)[3] = 0;
    }

    __shared__ __align__(16) float As[KT][ASTR];   // transposed: As[k][row]
    __shared__ __align__(16) float Bs[KT][BSTR];
    const int tid = threadIdx.x;
    const int tx = tid & 15;          // col group: j = bj + tx*4
    const int ty = tid >> 4;          // row group: i = bi + ty*8
    const int bi = blockIdx.x * TR;
    const int bj = blockIdx.y * TC;
    const int k0 = blockIdx.z * KT;

    // Stage transposed. Global float4 coalesced; scalar LDS writes (~4-way).
    {
        const int r0 = tid >> 3;          // 0..31
        const int kc = (tid & 7) * 4;     // 0,4,..,28
#pragma unroll
        for (int p = 0; p < 4; ++p) {
            const int row = p * 32 + r0;
            float4 v = *(const float4*)(E + (size_t)(bi + row) * BSZ + k0 + kc);
            As[kc  ][row] = v.x; As[kc+1][row] = v.y; As[kc+2][row] = v.z; As[kc+3][row] = v.w;
        }
#pragma unroll
        for (int p = 0; p < 2; ++p) {
            const int row = p * 32 + r0;
            float4 v = *(const float4*)(E + (size_t)(bj + row) * BSZ + k0 + kc);
            Bs[kc  ][row] = v.x; Bs[kc+1][row] = v.y; Bs[kc+2][row] = v.z; Bs[kc+3][row] = v.w;
        }
    }
    __syncthreads();

    float acc[8][4];
#pragma unroll
    for (int r = 0; r < 8; ++r)
#pragma unroll
        for (int c = 0; c < 4; ++c) acc[r][c] = 0.0f;

#pragma unroll 4
    for (int kk = 0; kk < KT; ++kk) {
        // A: 4 addrs/wave (broadcast x16), banks 8*ty -> conflict-free.
        float4 A0 = *(const float4*)&As[kk][ty * 8];
        float4 A1 = *(const float4*)&As[kk][ty * 8 + 4];
        // B: 16 addrs/wave, banks 4*tx -> 2-way (free).
        float4 B0 = *(const float4*)&Bs[kk][tx * 4];
        float ar[8] = {A0.x, A0.y, A0.z, A0.w, A1.x, A1.y, A1.z, A1.w};
        float br[4] = {B0.x, B0.y, B0.z, B0.w};
#pragma unroll
        for (int r = 0; r < 8; ++r)
#pragma unroll
            for (int c = 0; c < 4; ++c) {
                float d = ar[r] - br[c];
                acc[r][c] = fmaf(d, d, acc[r][c]);
            }
    }

    float* Pp = ws + WS_P + (size_t)blockIdx.z * BSZ * BSZ;
#pragma unroll
    for (int r = 0; r < 8; ++r) {   // 16 lanes x float4 = 256B contiguous per row
        float4 v = {acc[r][0], acc[r][1], acc[r][2], acc[r][3]};
        *(float4*)(Pp + (size_t)(bi + ty * 8 + r) * BSZ + bj + tx * 4) = v;
    }
}

// ---- Kernel 2: per-anchor triplet sums + decoupled last-block finale ----
__global__ __launch_bounds__(256) void triplet_kernel(const int* __restrict__ labels,
                                                      float* __restrict__ ws,
                                                      float* __restrict__ out) {
    const int a = blockIdx.x;
    const int tid = threadIdx.x;
    __shared__ float drow[BSZ];
    __shared__ int   lab[BSZ];
    __shared__ int   poslist[BSZ];
    __shared__ int   npos_s;
    __shared__ float wsum[4];
    __shared__ int   wcnt[4];
    __shared__ int   is_last;

    if (tid == 0) npos_s = 0;
    for (int t = tid; t < BSZ; t += 256) lab[t] = labels[t];

    const float* P = ws + WS_P;
    if (tid < 128) {   // 128 threads x float4 = 512 cols; sum NS chunk partials
        float4 s4 = {0.f, 0.f, 0.f, 0.f};
#pragma unroll
        for (int s = 0; s < NS; ++s) {
            float4 v = *(const float4*)(P + ((size_t)s * BSZ + a) * BSZ + tid * 4);
            s4.x += v.x; s4.y += v.y; s4.z += v.z; s4.w += v.w;
        }
        drow[tid * 4 + 0] = dist_xform(s4.x);
        drow[tid * 4 + 1] = dist_xform(s4.y);
        drow[tid * 4 + 2] = dist_xform(s4.z);
        drow[tid * 4 + 3] = dist_xform(s4.w);
    }
    __syncthreads();

    const int la = lab[a];
    for (int t = tid; t < BSZ; t += 256) {
        if (lab[t] == la && t != a) {
            int idx = atomicAdd(&npos_s, 1);
            poslist[idx] = t;
        }
    }
    __syncthreads();

    const int npos = npos_s;
    const int nneg = BSZ - 1 - npos;
    float sum = 0.0f;
    int   cnt = 0;
    const int total = npos * BSZ;
    for (int idx = tid; idx < total; idx += 256) {
        const int p = poslist[idx >> 9];   // broadcast within wave
        const int n = idx & (BSZ - 1);     // consecutive -> conflict-free
        if (lab[n] != la) {
            const float v = drow[p] - drow[n];   // margin = 0
            if (v > 0.0f)  sum += v;
            if (v > 1e-5f) cnt++;
        }
    }
#pragma unroll
    for (int off = 32; off > 0; off >>= 1) {
        sum += __shfl_down(sum, off);
        cnt += __shfl_down(cnt, off);
    }
    const int wave = tid >> 6, lane = tid & 63;
    if (lane == 0) { wsum[wave] = sum; wcnt[wave] = cnt; }
    __syncthreads();

    float* partial = ws + WS_PARTIAL;
    if (tid == 0) {
        partial[a]           = wsum[0] + wsum[1] + wsum[2] + wsum[3];
        partial[BSZ + a]     = (float)(wcnt[0] + wcnt[1] + wcnt[2] + wcnt[3]);
        partial[2*BSZ + a]   = (float)npos * (float)nneg;
        __threadfence();                        // release: partials visible device-wide
        int old = atomicAdd((int*)ws + 3, 1);   // device-scope counter
        is_last = (old == BSZ - 1) ? 1 : 0;
    }
    __syncthreads();

    if (is_last) {   // exactly one block runs the finale (standard decoupled pattern)
        __threadfence();                        // acquire: invalidate stale caches
        float s = partial[tid]         + partial[tid + 256];
        float c = partial[BSZ + tid]   + partial[BSZ + tid + 256];
        float v = partial[2*BSZ + tid] + partial[2*BSZ + tid + 256];
#pragma unroll
        for (int off = 32; off > 0; off >>= 1) {
            s += __shfl_down(s, off);
            c += __shfl_down(c, off);
            v += __shfl_down(v, off);
        }
        if (lane == 0) { wsum[wave] = s; wcnt[wave] = (int)c; drow[wave] = v; }
        __syncthreads();
        if (tid == 0) {
            float S = wsum[0] + wsum[1] + wsum[2] + wsum[3];
            float C = (float)(wcnt[0] + wcnt[1] + wcnt[2] + wcnt[3]);
            float V = drow[0] + drow[1] + drow[2] + drow[3];
            out[0] = S / (C + 1e-5f);   // loss
            out[1] = C / (V + 1e-5f);   // fraction_positive
        }
    }
}

extern "C" void kernel_launch(void* const* d_in, const int* in_sizes, int n_in,
                              void* d_out, int out_size, void* d_ws, size_t ws_size,
                              hipStream_t stream) {
    const float* E      = (const float*)d_in[0];   // embeddings [512,512] fp32
    const int*   labels = (const int*)d_in[1];     // labels [512]
    float* out = (float*)d_out;
    float* ws  = (float*)d_ws;

    dsq_kernel<<<dim3(4, 8, NS), 256, 0, stream>>>(E, ws);
    triplet_kernel<<<BSZ, 256, 0, stream>>>(labels, ws, out);
}